// Round 1
// baseline (107.683 us; speedup 1.0000x reference)
//
#include <hip/hip_runtime.h>

namespace {
constexpr int MD = 4;
constexpr int BB = 8, CC = 128, HH = 96, WW = 192;
constexpr int TH = 4, TW = 64;
constexpr int NROWS = TH + 2 * MD;      // 12 staged rows
constexpr int ROWF  = 80;               // floats staged per row (w0-8 .. w0+71)
constexpr int LSTR  = 84;               // padded LDS row stride (floats), keeps 16B align
constexpr int NF4   = NROWS * (ROWF / 4);  // 240 float4 per channel
}

__global__ __launch_bounds__(192, 2)
void corr81(const float* __restrict__ in0,
            const float* __restrict__ in1,
            float* __restrict__ out)
{
    const int tid  = threadIdx.x;
    const int wv   = tid >> 6;          // wave 0..2 -> displacement rows
    const int lane = tid & 63;
    const int g    = lane >> 4;         // h-row within tile (0..3)
    const int q    = lane & 15;         // w-group: owns w0+q*4 .. +3

    const int w0 = blockIdx.x * TW;
    const int h0 = blockIdx.y * TH;
    const int b  = blockIdx.z;

    __shared__ float lds[NROWS][LSTR];

    const size_t plane = (size_t)HH * WW;
    const size_t img   = (size_t)CC * plane;

    const float* in1b = in1 + (size_t)b * img;

    // staging slot(s) for this thread: float4 index f -> (row f/20, col (f%20)*4)
    const int f0 = tid;
    const int r0 = f0 / 20, c0 = (f0 % 20) * 4;
    const int f1 = tid + 192;
    const int r1 = f1 / 20, c1 = (f1 % 20) * 4;
    const bool has1 = (f1 < NF4);

    const int grow0 = h0 - MD + r0, gcol0 = w0 - 8 + c0;
    const int grow1 = h0 - MD + r1, gcol1 = w0 - 8 + c1;
    const bool ok0 = (grow0 >= 0 && grow0 < HH && gcol0 >= 0 && gcol0 < WW);
    const bool ok1 = has1 && (grow1 >= 0 && grow1 < HH && gcol1 >= 0 && gcol1 < WW);

    const float* p0 = in1b + (size_t)grow0 * WW + gcol0;
    const float* p1 = in1b + (size_t)grow1 * WW + gcol1;
    const float* pa = in0 + (size_t)b * img + (size_t)(h0 + g) * WW + (w0 + q * 4);

    float acc[3][9][4];
    #pragma unroll
    for (int rr = 0; rr < 3; ++rr)
        #pragma unroll
        for (int cc = 0; cc < 9; ++cc)
            #pragma unroll
            for (int j = 0; j < 4; ++j) acc[rr][cc][j] = 0.f;

    float4 s0 = ok0 ? *(const float4*)p0 : make_float4(0.f, 0.f, 0.f, 0.f);
    float4 s1 = ok1 ? *(const float4*)p1 : make_float4(0.f, 0.f, 0.f, 0.f);

    for (int c = 0; c < CC; ++c) {
        __syncthreads();                      // previous iter done reading LDS
        *(float4*)&lds[r0][c0] = s0;
        if (has1) *(float4*)&lds[r1][c1] = s1;
        const float4 a = *(const float4*)pa;
        pa += plane;
        __syncthreads();
        if (c + 1 < CC) {                     // prefetch next channel under compute
            p0 += plane; p1 += plane;
            s0 = ok0 ? *(const float4*)p0 : make_float4(0.f, 0.f, 0.f, 0.f);
            s1 = ok1 ? *(const float4*)p1 : make_float4(0.f, 0.f, 0.f, 0.f);
        }
        const float av[4] = {a.x, a.y, a.z, a.w};
        #pragma unroll
        for (int rr = 0; rr < 3; ++rr) {
            const int row = g + wv * 3 + rr;  // LDS row = g + (r+4)
            const float4 wA = *(const float4*)&lds[row][q * 4 + 4];
            const float4 wB = *(const float4*)&lds[row][q * 4 + 8];
            const float4 wC = *(const float4*)&lds[row][q * 4 + 12];
            const float win[12] = {wA.x, wA.y, wA.z, wA.w,
                                   wB.x, wB.y, wB.z, wB.w,
                                   wC.x, wC.y, wC.z, wC.w};
            #pragma unroll
            for (int cc = 0; cc < 9; ++cc)
                #pragma unroll
                for (int j = 0; j < 4; ++j)
                    acc[rr][cc][j] = fmaf(av[j], win[cc + j], acc[rr][cc][j]);
        }
    }

    const float scale = 1.0f / CC;
    float* ob = out + ((size_t)b * 81) * plane + (size_t)(h0 + g) * WW + (w0 + q * 4);
    #pragma unroll
    for (int rr = 0; rr < 3; ++rr) {
        const int dbase = (wv * 3 + rr) * 9;
        #pragma unroll
        for (int cc = 0; cc < 9; ++cc) {
            float4 o = make_float4(acc[rr][cc][0] * scale, acc[rr][cc][1] * scale,
                                   acc[rr][cc][2] * scale, acc[rr][cc][3] * scale);
            *(float4*)(ob + (size_t)(dbase + cc) * plane) = o;
        }
    }
}

extern "C" void kernel_launch(void* const* d_in, const int* in_sizes, int n_in,
                              void* d_out, int out_size, void* d_ws, size_t ws_size,
                              hipStream_t stream)
{
    const float* in0 = (const float*)d_in[0];
    const float* in1 = (const float*)d_in[1];
    float* out = (float*)d_out;
    dim3 grid(WW / TW, HH / TH, BB);   // 3 x 24 x 8 = 576 blocks
    corr81<<<grid, dim3(192), 0, stream>>>(in0, in1, out);
}